// Round 5
// baseline (258.092 us; speedup 1.0000x reference)
//
#include <hip/hip_runtime.h>

// MovementEmbeddingModule: bs=4, d=16, K=10, C=3, h=w=128
// out: (4, 60, 16, 128, 128) f32; out[b][k*6+c][d][y][x]
#define BS 4
#define DD 16
#define KK 10
#define CC 3
#define HH 128
#define WW 128

#define NROWS 9     // 8 output rows per block -> 9 source rows
#define LROW 132    // 129 staged cols, padded to 132 (16B-multiple row stride)

typedef float f32x4 __attribute__((ext_vector_type(4)));   // native vector: OK for nontemporal builtins

__global__ __launch_bounds__(256) void movement_embed_kernel(
    const float* __restrict__ kp_app,   // (4,1,10,2)
    const float* __restrict__ kp_vid,   // (4,16,10,2)
    const float* __restrict__ img,      // (4,3,128,128)
    float* __restrict__ out)
{
    __shared__ __align__(16) float P[CC][NROWS][LROW];  // 14,256 B

    const unsigned bi  = blockIdx.x;
    const unsigned sub = bi & 15u;          // 16 row-tiles (8 rows each) per (b,d,k)
    const unsigned bdk = bi >> 4;
    const unsigned k   = bdk % KK;
    const unsigned t2  = bdk / KK;
    const unsigned d   = t2 % DD;
    const unsigned b   = t2 / DD;
    const int tid  = (int)threadIdx.x;
    const int lane = tid & 63;
    const int wv   = tid >> 6;              // wave id 0..3

    // wave-uniform keypoint math (SGPR path)
    const float kvx  = kp_vid[((b*DD + d)*KK + k)*2 + 0];
    const float kvy  = kp_vid[((b*DD + d)*KK + k)*2 + 1];
    const float kv0x = kp_vid[((b*DD + 0)*KK + k)*2 + 0];
    const float kv0y = kp_vid[((b*DD + 0)*KK + k)*2 + 1];
    const float kax  = kp_app[(b*KK + k)*2 + 0];
    const float kay  = kp_app[(b*KK + k)*2 + 1];

    const float diffx = kvx - kv0x;     // exactly 0 at d==0
    const float diffy = kvy - kv0y;
    const float mx = diffx + kax;       // heatmap center
    const float my = diffy + kay;
    const float vdx = -diffx;           // kp_video_diff (diff-map consts + warp shift)
    const float vdy = -diffy;

    // Uniform bilinear decomposition: sample coord = pixel + c (step*(W-1)/2 == 1.0)
    const float cx = vdx * 63.5f;
    const float cy = vdy * 63.5f;
    const float fcx = floorf(cx);
    const float fcy = floorf(cy);
    const int icx = (int)fcx;
    const int icy = (int)fcy;
    const float wx1 = cx - fcx, wx0 = 1.0f - wx1;   // block-uniform weights
    const float wy1 = cy - fcy, wy0 = 1.0f - wy1;

    const int R0 = (int)(sub * 8u) + icy;           // first source row
    const float* imgb = img + (size_t)b * (CC*HH*WW);

    // ---- kick off LDS staging: 3ch x 9 rows x 129 cols, zero-padded ----
    // Fully unrolled (c,ri) tasks striped over the 4 waves; clamped addrs +
    // cndmask zeroing (no divergent branches, no integer division).
#pragma unroll
    for (int c = 0; c < CC; ++c) {
        const float* pc = imgb + c * (HH * WW);
#pragma unroll
        for (int ri = 0; ri < NROWS; ++ri) {
            if (((c * NROWS + ri) & 3) == wv) {     // wave-uniform scalar predicate
                const int  r   = R0 + ri;
                const bool rok = (unsigned)r < (unsigned)HH;
                const float* rp = pc + (size_t)min(max(r, 0), HH - 1) * WW;

                const int c0 = icx + lane;
                const int c1 = c0 + 64;
                float v0 = rp[min(max(c0, 0), WW - 1)];
                float v1 = rp[min(max(c1, 0), WW - 1)];
                v0 = (rok && (unsigned)c0 < (unsigned)WW) ? v0 : 0.0f;
                v1 = (rok && (unsigned)c1 < (unsigned)WW) ? v1 : 0.0f;
                P[c][ri][lane]      = v0;
                P[c][ri][lane + 64] = v1;
                if (lane == 0) {                    // col 128 tail
                    const int c2 = icx + 128;
                    float v2 = rp[min(max(c2, 0), WW - 1)];
                    P[c][ri][128] = (rok && (unsigned)c2 < (unsigned)WW) ? v2 : 0.0f;
                }
            }
        }
    }

    // ---- LDS-independent work BEFORE the barrier: overlaps staging latency ----
    const int xg = tid & 31;        // float4 column
    const int ly = tid >> 5;        // local row 0..7
    const int x4 = xg * 4;
    const int y  = (int)(sub * 8u) + ly;

    const float step = 2.0f / 127.0f;
    const float gy  = (float)y  * step - 1.0f;
    const float gx0 = (float)x4 * step - 1.0f;

    // heatmap: exp(-50*r^2(kp_mean)) - exp(-50*r^2(kp_app)); exact 0 at d==0
    const float dy1 = gy - my, dy0 = gy - kay;
    const float dy1sq = dy1 * dy1, dy0sq = dy0 * dy0;
    float hv[4];
#pragma unroll
    for (int j = 0; j < 4; ++j) {
        const float gx = gx0 + (float)j * step;
        const float dx1 = gx - mx, dx0 = gx - kax;
        hv[j] = __expf(-50.0f * (dx1 * dx1 + dy1sq))
              - __expf(-50.0f * (dx0 * dx0 + dy0sq));
    }

    // stores: out[b][k*6+c][d][y][x]; streaming (nontemporal) — never re-read
    const size_t chs  = (size_t)DD * HH * WW;  // 262144
    const size_t base = ((((size_t)b * (KK * 6) + k * 6) * DD + d) * HH + y) * WW + (size_t)x4;

    {
        const f32x4 hvv = { hv[0], hv[1], hv[2], hv[3] };
        const f32x4 vxv = { vdx, vdx, vdx, vdx };
        const f32x4 vyv = { vdy, vdy, vdy, vdy };
        __builtin_nontemporal_store(hvv, (f32x4*)(out + base));
        __builtin_nontemporal_store(vxv, (f32x4*)(out + base + chs));
        __builtin_nontemporal_store(vyv, (f32x4*)(out + base + 2*chs));
    }

    __syncthreads();

    // ---- deformed: uniform-weight blend of shifted rows from LDS ----
#pragma unroll
    for (int c = 0; c < CC; ++c) {
        const float* row0 = &P[c][ly][x4];
        const float* row1 = &P[c][ly + 1][x4];
        const f32x4 A = *(const f32x4*)row0;
        const float ea = row0[4];
        const f32x4 B = *(const f32x4*)row1;
        const float eb = row1[4];
        const float h0x = wx0 * A.x + wx1 * A.y;
        const float h0y = wx0 * A.y + wx1 * A.z;
        const float h0z = wx0 * A.z + wx1 * A.w;
        const float h0w = wx0 * A.w + wx1 * ea;
        const float h1x = wx0 * B.x + wx1 * B.y;
        const float h1y = wx0 * B.y + wx1 * B.z;
        const float h1z = wx0 * B.z + wx1 * B.w;
        const float h1w = wx0 * B.w + wx1 * eb;
        const f32x4 dv = { wy0 * h0x + wy1 * h1x,
                           wy0 * h0y + wy1 * h1y,
                           wy0 * h0z + wy1 * h1z,
                           wy0 * h0w + wy1 * h1w };
        __builtin_nontemporal_store(dv, (f32x4*)(out + base + (size_t)(3 + c) * chs));
    }
}

extern "C" void kernel_launch(void* const* d_in, const int* in_sizes, int n_in,
                              void* d_out, int out_size, void* d_ws, size_t ws_size,
                              hipStream_t stream) {
    const float* kp_app = (const float*)d_in[0];   // (4,1,10,2)
    const float* kp_vid = (const float*)d_in[1];   // (4,16,10,2)
    const float* img    = (const float*)d_in[2];   // (4,3,1,128,128)
    float* out = (float*)d_out;                    // (4,60,16,128,128)

    const int nblocks = BS * DD * KK * 16;         // 10240
    movement_embed_kernel<<<nblocks, 256, 0, stream>>>(kp_app, kp_vid, img, out);
}